// Round 1
// baseline (205.591 us; speedup 1.0000x reference)
//
#include <hip/hip_runtime.h>

#define NB 16384
#define XD 784
#define ZD 64
#define KK 64
#define LOG2PI_F 1.8378770664093453f

// ws layout (doubles): [0]=log_px quadratic acc, [1]=kl_y acc, [2]=kl_z acc

__device__ __forceinline__ float wave_sum(float x) {
    #pragma unroll
    for (int o = 32; o > 0; o >>= 1) x += __shfl_xor(x, o, 64);
    return x;
}

__device__ __forceinline__ float wave_max(float x) {
    #pragma unroll
    for (int o = 32; o > 0; o >>= 1) x = fmaxf(x, __shfl_xor(x, o, 64));
    return x;
}

__global__ void zero_acc_kernel(double* acc) {
    if (threadIdx.x < 3) acc[threadIdx.x] = 0.0;
}

// One wave per row b; lane doubles as z-index (loads) and k-index (component loop).
__global__ __launch_bounds__(256) void mixture_kernel(
    const float* __restrict__ pi, const float* __restrict__ qmu,
    const float* __restrict__ qls, const float* __restrict__ eps,
    const float* __restrict__ pmu_g, const float* __restrict__ plog_g,
    double* __restrict__ acc)
{
    __shared__ float2 pairT[ZD * KK];   // [v][k] = (pmu[k][v], 0.5*exp(-2*plog[k][v]))
    __shared__ float4 zq_s[4][ZD];      // per-wave (z, qmu, qs^2, _)
    __shared__ float Ck_s[KK], Sk_s[KK];
    __shared__ float r1[4], r2[4];

    const int tid  = threadIdx.x;
    const int lane = tid & 63;
    const int wid  = tid >> 6;

    // Build transposed tables (coalesced global reads; scattered LDS writes, one-time)
    for (int idx = tid; idx < ZD * KK; idx += 256) {
        int k = idx >> 6, v = idx & 63;
        float mu = pmu_g[idx];
        float lg = plog_g[idx];
        float i2 = 0.5f * __expf(-2.0f * lg);
        pairT[v * KK + k] = make_float2(mu, i2);
    }
    if (tid < KK) {
        float s = 0.f;
        for (int v = 0; v < ZD; ++v) s += plog_g[tid * ZD + v];
        Sk_s[tid] = s;
        Ck_s[tid] = -s - 32.0f * LOG2PI_F;   // sum_v(-plog) - 0.5*LOG2PI*ZD
    }
    __syncthreads();

    float acc_kly = 0.f, acc_klz = 0.f;
    const int gw = blockIdx.x * 4 + wid;    // 4096 global waves

    #pragma unroll 1
    for (int it = 0; it < 4; ++it) {
        const int b = gw + it * 4096;
        // per-lane v = lane
        float mu  = qmu[b * 64 + lane];
        float ls  = qls[b * 64 + lane];
        float ep  = eps[b * 64 + lane];
        float qsv = __expf(ls);
        float zv  = fmaf(qsv, ep, mu);
        float sum_qls = wave_sum(ls);
        zq_s[wid][lane] = make_float4(zv, mu, qsv * qsv, 0.f);
        __syncthreads();

        // per-lane k = lane
        const int k = lane;
        float a = 0.f, c = 0.f;
        #pragma unroll 16
        for (int v = 0; v < ZD; ++v) {
            float2 pr = pairT[v * KK + k];   // ds_read_b64, conflict-free
            float4 t  = zq_s[wid][v];        // broadcast ds_read_b128
            float dz = t.x - pr.x;
            a = fmaf(dz * dz, pr.y, a);
            float dm = t.y - pr.x;
            c = fmaf(fmaf(dm, dm, t.z), pr.y, c);
        }
        float comp = Ck_s[k] - a;                      // comp_lp[b,k]
        float pzy  = comp + __logf(pi[b * 64 + k]);
        float M = wave_max(pzy);
        float e = __expf(pzy - M);
        float S = wave_sum(e);
        float lse = M + __logf(S);
        float p = e / S;                               // exp(pzy - lse)
        acc_kly += p * (comp - lse);                   // p*(log_py_z - log_pi)
        acc_klz += p * (Sk_s[k] - sum_qls + c - 32.0f);
    }

    float s1 = wave_sum(acc_kly);
    float s2 = wave_sum(acc_klz);
    if (lane == 0) { r1[wid] = s1; r2[wid] = s2; }
    __syncthreads();
    if (tid == 0) {
        atomicAdd(&acc[1], (double)(r1[0] + r1[1] + r1[2] + r1[3]));
        atomicAdd(&acc[2], (double)(r2[0] + r2[1] + r2[2] + r2[3]));
    }
}

// 16 rows per block; 256 threads over columns; z tile recomputed into LDS,
// broadcast float4 reads; W streamed from L2 (reused across 16-row register tile).
__global__ __launch_bounds__(256) void decoder_kernel(
    const float* __restrict__ x, const float* __restrict__ qmu,
    const float* __restrict__ qls, const float* __restrict__ eps,
    const float* __restrict__ W, const float* __restrict__ bd,
    double* __restrict__ acc)
{
    __shared__ float z_s[16 * 64];
    __shared__ float rs[4];
    const int tid  = threadIdx.x;
    const int row0 = blockIdx.x * 16;

    for (int idx = tid; idx < 16 * 64; idx += 256) {
        int g = row0 * 64 + idx;
        z_s[idx] = fmaf(__expf(qls[g]), eps[g], qmu[g]);
    }
    __syncthreads();

    float accl = 0.f;
    #pragma unroll 1
    for (int jt = 0; jt < 4; ++jt) {
        const int j = jt * 256 + tid;
        if (j < XD) {
            float m[16];
            float b0 = bd[j];
            #pragma unroll
            for (int r = 0; r < 16; ++r) m[r] = b0;
            #pragma unroll 4
            for (int zc = 0; zc < 16; ++zc) {
                float w0 = W[(zc * 4 + 0) * XD + j];
                float w1 = W[(zc * 4 + 1) * XD + j];
                float w2 = W[(zc * 4 + 2) * XD + j];
                float w3 = W[(zc * 4 + 3) * XD + j];
                #pragma unroll
                for (int r = 0; r < 16; ++r) {
                    float4 zv = *(const float4*)&z_s[r * 64 + zc * 4];
                    m[r] = fmaf(zv.x, w0, m[r]);
                    m[r] = fmaf(zv.y, w1, m[r]);
                    m[r] = fmaf(zv.z, w2, m[r]);
                    m[r] = fmaf(zv.w, w3, m[r]);
                }
            }
            #pragma unroll
            for (int r = 0; r < 16; ++r) {
                float d = x[(row0 + r) * XD + j] - m[r];
                accl = fmaf(d, d, accl);
            }
        }
    }

    float s = wave_sum(accl);
    const int lane = tid & 63, wid = tid >> 6;
    if (lane == 0) rs[wid] = s;
    __syncthreads();
    if (tid == 0)
        atomicAdd(&acc[0], (double)(-0.5f * (rs[0] + rs[1] + rs[2] + rs[3])));
}

__global__ void finalize_kernel(const double* __restrict__ acc, float* __restrict__ out) {
    if (threadIdx.x == 0) {
        double lpx = acc[0] - 0.5 * 1.8378770664093453 * (double)NB * (double)XD;
        double elbo = (lpx - acc[1] - acc[2]) / (double)NB;
        out[0] = (float)elbo;
    }
}

extern "C" void kernel_launch(void* const* d_in, const int* in_sizes, int n_in,
                              void* d_out, int out_size, void* d_ws, size_t ws_size,
                              hipStream_t stream) {
    const float* x    = (const float*)d_in[0];
    const float* pi   = (const float*)d_in[1];
    const float* qmu  = (const float*)d_in[2];
    const float* qls  = (const float*)d_in[3];
    const float* eps  = (const float*)d_in[4];
    const float* pmu  = (const float*)d_in[5];
    const float* plog = (const float*)d_in[6];
    const float* W    = (const float*)d_in[7];
    const float* bd   = (const float*)d_in[8];
    float* out = (float*)d_out;
    double* acc = (double*)d_ws;

    zero_acc_kernel<<<1, 64, 0, stream>>>(acc);
    mixture_kernel<<<1024, 256, 0, stream>>>(pi, qmu, qls, eps, pmu, plog, acc);
    decoder_kernel<<<NB / 16, 256, 0, stream>>>(x, qmu, qls, eps, W, bd, acc);
    finalize_kernel<<<1, 64, 0, stream>>>(acc, out);
}

// Round 2
// 173.523 us; speedup vs baseline: 1.1848x; 1.1848x over previous
//
#include <hip/hip_runtime.h>

#define NB 16384
#define XD 784
#define ZD 64
#define KK 64
#define LOG2PI_F 1.8378770664093453f

typedef __attribute__((ext_vector_type(8))) short short8;
typedef __attribute__((ext_vector_type(4))) float floatx4;

// ws layout: [0..2] doubles: log_px quad acc, kl_y acc, kl_z acc
//            +256 bytes: Wt[784][64] bf16 (transposed decoder weight)

__device__ __forceinline__ float wave_sum(float x) {
    #pragma unroll
    for (int o = 32; o > 0; o >>= 1) x += __shfl_xor(x, o, 64);
    return x;
}

__device__ __forceinline__ float wave_max(float x) {
    #pragma unroll
    for (int o = 32; o > 0; o >>= 1) x = fmaxf(x, __shfl_xor(x, o, 64));
    return x;
}

__device__ __forceinline__ unsigned short f2bf(float f) {
    unsigned u = __float_as_uint(f);
    unsigned r = (u + 0x7FFF + ((u >> 16) & 1)) >> 16;  // RNE
    return (unsigned short)r;
}

// Zero accumulators + build transposed bf16 weight Wt[n][k] from W[k][n].
__global__ __launch_bounds__(256) void prep_kernel(
    const float* __restrict__ W, unsigned short* __restrict__ Wt, double* __restrict__ acc)
{
    if (blockIdx.x == 0 && threadIdx.x < 3) acc[threadIdx.x] = 0.0;
    int idx = blockIdx.x * 256 + threadIdx.x;
    if (idx < ZD * XD) {
        int k = idx / XD;
        int n = idx - k * XD;
        Wt[n * ZD + k] = f2bf(W[idx]);   // coalesced read, scattered 2B write (100 KB total)
    }
}

// One wave per row b; lane doubles as z-index (loads) and k-index (component loop).
__global__ __launch_bounds__(256) void mixture_kernel(
    const float* __restrict__ pi, const float* __restrict__ qmu,
    const float* __restrict__ qls, const float* __restrict__ eps,
    const float* __restrict__ pmu_g, const float* __restrict__ plog_g,
    double* __restrict__ acc)
{
    __shared__ float2 pairT[ZD * KK];   // [v][k] = (pmu[k][v], 0.5*exp(-2*plog[k][v]))
    __shared__ float4 zq_s[4][ZD];      // per-wave (z, qmu, qs^2, _)
    __shared__ float Ck_s[KK], Sk_s[KK];
    __shared__ float r1[4], r2[4];

    const int tid  = threadIdx.x;
    const int lane = tid & 63;
    const int wid  = tid >> 6;

    for (int idx = tid; idx < ZD * KK; idx += 256) {
        int k = idx >> 6, v = idx & 63;
        float mu = pmu_g[idx];
        float lg = plog_g[idx];
        float i2 = 0.5f * __expf(-2.0f * lg);
        pairT[v * KK + k] = make_float2(mu, i2);
    }
    if (tid < KK) {
        float s = 0.f;
        for (int v = 0; v < ZD; ++v) s += plog_g[tid * ZD + v];
        Sk_s[tid] = s;
        Ck_s[tid] = -s - 32.0f * LOG2PI_F;
    }
    __syncthreads();

    float acc_kly = 0.f, acc_klz = 0.f;
    const int gw = blockIdx.x * 4 + wid;

    #pragma unroll 1
    for (int it = 0; it < 4; ++it) {
        const int b = gw + it * 4096;
        float mu  = qmu[b * 64 + lane];
        float ls  = qls[b * 64 + lane];
        float ep  = eps[b * 64 + lane];
        float qsv = __expf(ls);
        float zv  = fmaf(qsv, ep, mu);
        float sum_qls = wave_sum(ls);
        zq_s[wid][lane] = make_float4(zv, mu, qsv * qsv, 0.f);
        __syncthreads();

        const int k = lane;
        float a = 0.f, c = 0.f;
        #pragma unroll 16
        for (int v = 0; v < ZD; ++v) {
            float2 pr = pairT[v * KK + k];
            float4 t  = zq_s[wid][v];
            float dz = t.x - pr.x;
            a = fmaf(dz * dz, pr.y, a);
            float dm = t.y - pr.x;
            c = fmaf(fmaf(dm, dm, t.z), pr.y, c);
        }
        float comp = Ck_s[k] - a;
        float pzy  = comp + __logf(pi[b * 64 + k]);
        float M = wave_max(pzy);
        float e = __expf(pzy - M);
        float S = wave_sum(e);
        float lse = M + __logf(S);
        float p = e / S;
        acc_kly += p * (comp - lse);
        acc_klz += p * (Sk_s[k] - sum_qls + c - 32.0f);
    }

    float s1 = wave_sum(acc_kly);
    float s2 = wave_sum(acc_klz);
    if (lane == 0) { r1[wid] = s1; r2[wid] = s2; }
    __syncthreads();
    if (tid == 0) {
        atomicAdd(&acc[1], (double)(r1[0] + r1[1] + r1[2] + r1[3]));
        atomicAdd(&acc[2], (double)(r2[0] + r2[1] + r2[2] + r2[3]));
    }
}

// MFMA decoder: 16 rows/block, 4 waves split the 49 column tiles.
// mean = z@W + b via mfma_f32_16x16x32_bf16; epilogue accumulates (x-mean)^2.
// A-frag: A[m=lane&15][k=quad*8+j]; B-frag: B[k=quad*8+j][n=lane&15];
// C/D: col=lane&15, row=quad*4+reg (learn_hip m89/m91 verified mapping).
__global__ __launch_bounds__(256) void decoder_mfma_kernel(
    const float* __restrict__ x, const float* __restrict__ qmu,
    const float* __restrict__ qls, const float* __restrict__ eps,
    const unsigned short* __restrict__ Wt, const float* __restrict__ bd,
    double* __restrict__ acc)
{
    __shared__ unsigned short zt[16 * 64];  // bf16 z tile
    __shared__ float rs[4];
    const int tid  = threadIdx.x;
    const int row0 = blockIdx.x * 16;

    for (int i = tid; i < 16 * 64; i += 256) {
        int g = row0 * 64 + i;
        float z = fmaf(__expf(qls[g]), eps[g], qmu[g]);
        zt[i] = f2bf(z);
    }
    __syncthreads();

    const int lane = tid & 63;
    const int wid  = tid >> 6;
    const int m    = lane & 15;
    const int quad = lane >> 4;

    const short8 af0 = *(const short8*)&zt[m * 64 + quad * 8];
    const short8 af1 = *(const short8*)&zt[m * 64 + 32 + quad * 8];

    float accl = 0.f;
    #pragma unroll 1
    for (int t = wid; t < 49; t += 4) {
        const int col = t * 16 + m;
        // issue x loads early so they overlap the MFMAs
        float x0 = x[(row0 + quad * 4 + 0) * XD + col];
        float x1 = x[(row0 + quad * 4 + 1) * XD + col];
        float x2 = x[(row0 + quad * 4 + 2) * XD + col];
        float x3 = x[(row0 + quad * 4 + 3) * XD + col];
        float b0 = bd[col];
        const short8 bf0 = *(const short8*)&Wt[col * 64 + quad * 8];
        const short8 bf1 = *(const short8*)&Wt[col * 64 + 32 + quad * 8];
        floatx4 c = {0.f, 0.f, 0.f, 0.f};
        c = __builtin_amdgcn_mfma_f32_16x16x32_bf16(af0, bf0, c, 0, 0, 0);
        c = __builtin_amdgcn_mfma_f32_16x16x32_bf16(af1, bf1, c, 0, 0, 0);
        float d0 = x0 - (c[0] + b0);
        float d1 = x1 - (c[1] + b0);
        float d2 = x2 - (c[2] + b0);
        float d3 = x3 - (c[3] + b0);
        accl = fmaf(d0, d0, accl);
        accl = fmaf(d1, d1, accl);
        accl = fmaf(d2, d2, accl);
        accl = fmaf(d3, d3, accl);
    }

    float s = wave_sum(accl);
    if (lane == 0) rs[wid] = s;
    __syncthreads();
    if (tid == 0)
        atomicAdd(&acc[0], (double)(-0.5f * (rs[0] + rs[1] + rs[2] + rs[3])));
}

__global__ void finalize_kernel(const double* __restrict__ acc, float* __restrict__ out) {
    if (threadIdx.x == 0) {
        double lpx = acc[0] - 0.5 * 1.8378770664093453 * (double)NB * (double)XD;
        double elbo = (lpx - acc[1] - acc[2]) / (double)NB;
        out[0] = (float)elbo;
    }
}

extern "C" void kernel_launch(void* const* d_in, const int* in_sizes, int n_in,
                              void* d_out, int out_size, void* d_ws, size_t ws_size,
                              hipStream_t stream) {
    const float* x    = (const float*)d_in[0];
    const float* pi   = (const float*)d_in[1];
    const float* qmu  = (const float*)d_in[2];
    const float* qls  = (const float*)d_in[3];
    const float* eps  = (const float*)d_in[4];
    const float* pmu  = (const float*)d_in[5];
    const float* plog = (const float*)d_in[6];
    const float* W    = (const float*)d_in[7];
    const float* bd   = (const float*)d_in[8];
    float* out = (float*)d_out;
    double* acc = (double*)d_ws;
    unsigned short* Wt = (unsigned short*)((char*)d_ws + 256);

    prep_kernel<<<(ZD * XD + 255) / 256, 256, 0, stream>>>(W, Wt, acc);
    mixture_kernel<<<1024, 256, 0, stream>>>(pi, qmu, qls, eps, pmu, plog, acc);
    decoder_mfma_kernel<<<NB / 16, 256, 0, stream>>>(x, qmu, qls, eps, Wt, bd, acc);
    finalize_kernel<<<1, 64, 0, stream>>>(acc, out);
}

// Round 3
// 136.777 us; speedup vs baseline: 1.5031x; 1.2687x over previous
//
#include <hip/hip_runtime.h>

#define NB 16384
#define XD 784
#define ZD 64
#define KK 64
#define LOG2PI_F 1.8378770664093453f
#define LDA 72   // padded row (shorts) for bf16 LDS tiles

typedef __attribute__((ext_vector_type(8))) short short8;
typedef __attribute__((ext_vector_type(4))) float floatx4;

// ws layout: [0..2] doubles: log_px quad acc, kl_y acc, kl_z acc
//            +256 bytes: Wt[784][64] bf16 (transposed decoder weight)

__device__ __forceinline__ float wave_sum(float x) {
    #pragma unroll
    for (int o = 32; o > 0; o >>= 1) x += __shfl_xor(x, o, 64);
    return x;
}

__device__ __forceinline__ unsigned short f2bf(float f) {
    unsigned u = __float_as_uint(f);
    unsigned r = (u + 0x7FFF + ((u >> 16) & 1)) >> 16;  // RNE
    return (unsigned short)r;
}

__device__ __forceinline__ unsigned int pack2(float a, float b) {
    return (unsigned int)f2bf(a) | ((unsigned int)f2bf(b) << 16);
}

// Zero accumulators + build transposed bf16 weight Wt[n][k] from W[k][n].
__global__ __launch_bounds__(256) void prep_kernel(
    const float* __restrict__ W, unsigned short* __restrict__ Wt, double* __restrict__ acc)
{
    if (blockIdx.x == 0 && threadIdx.x < 3) acc[threadIdx.x] = 0.0;
    int idx = blockIdx.x * 256 + threadIdx.x;
    if (idx < ZD * XD) {
        int k = idx / XD;
        int n = idx - k * XD;
        Wt[n * ZD + k] = f2bf(W[idx]);
    }
}

// MFMA mixture: 64 rows/block, 4 waves; wave w owns rows w*16..w*16+15 x all 64 k.
// a[b,k] = z^2 @ I2^T + (-2z) @ M1^T + G_k   (M1 = mu*i2)
// c[b,k] = (qmu^2+qs^2) @ I2^T + (-2qmu) @ M1^T + G_k
// comp = Ck - a; softmax over k in-wave (16-lane quad groups x 4 k-tiles).
__global__ __launch_bounds__(256) void mixture_mfma_kernel(
    const float* __restrict__ pi, const float* __restrict__ qmu,
    const float* __restrict__ qls, const float* __restrict__ eps,
    const float* __restrict__ pmu_g, const float* __restrict__ plog_g,
    double* __restrict__ acc)
{
    __shared__ unsigned short Az2[64 * LDA];  // z^2
    __shared__ unsigned short Azm[64 * LDA];  // -2z
    __shared__ unsigned short Aq2[64 * LDA];  // qmu^2 + qs^2
    __shared__ unsigned short Aqm[64 * LDA];  // -2*qmu
    __shared__ unsigned short Bi2[64 * LDA];  // i2[k][v]
    __shared__ unsigned short Bm1[64 * LDA];  // (mu*i2)[k][v]
    __shared__ float Ck_s[KK], Sk_s[KK], Gk_s[KK], sq_s[64];
    __shared__ float r1[4], r2[4];

    const int tid  = threadIdx.x;
    const int row0 = blockIdx.x * 64;

    // ---- stage A (per-row) ----
    {
        const int r  = tid >> 2;        // 0..63 local row
        const int q  = tid & 3;
        const int v0 = q * 16;
        const int gb = (row0 + r) * 64 + v0;
        float4 mu4[4], ls4[4], ep4[4];
        #pragma unroll
        for (int i = 0; i < 4; ++i) {
            mu4[i] = *(const float4*)&qmu[gb + 4 * i];
            ls4[i] = *(const float4*)&qls[gb + 4 * i];
            ep4[i] = *(const float4*)&eps[gb + 4 * i];
        }
        float sls = 0.f;
        unsigned int* pz2 = (unsigned int*)&Az2[r * LDA + v0];
        unsigned int* pzm = (unsigned int*)&Azm[r * LDA + v0];
        unsigned int* pq2 = (unsigned int*)&Aq2[r * LDA + v0];
        unsigned int* pqm = (unsigned int*)&Aqm[r * LDA + v0];
        #pragma unroll
        for (int i = 0; i < 4; ++i) {
            float m0[4] = {mu4[i].x, mu4[i].y, mu4[i].z, mu4[i].w};
            float l0[4] = {ls4[i].x, ls4[i].y, ls4[i].z, ls4[i].w};
            float e0[4] = {ep4[i].x, ep4[i].y, ep4[i].z, ep4[i].w};
            float z[4], q2[4];
            #pragma unroll
            for (int j = 0; j < 4; ++j) {
                float qs = __expf(l0[j]);
                z[j]  = fmaf(qs, e0[j], m0[j]);
                q2[j] = fmaf(m0[j], m0[j], qs * qs);
                sls += l0[j];
            }
            pz2[i * 2 + 0] = pack2(z[0] * z[0], z[1] * z[1]);
            pz2[i * 2 + 1] = pack2(z[2] * z[2], z[3] * z[3]);
            pzm[i * 2 + 0] = pack2(-2.f * z[0], -2.f * z[1]);
            pzm[i * 2 + 1] = pack2(-2.f * z[2], -2.f * z[3]);
            pq2[i * 2 + 0] = pack2(q2[0], q2[1]);
            pq2[i * 2 + 1] = pack2(q2[2], q2[3]);
            pqm[i * 2 + 0] = pack2(-2.f * m0[0], -2.f * m0[1]);
            pqm[i * 2 + 1] = pack2(-2.f * m0[2], -2.f * m0[3]);
        }
        sls += __shfl_xor(sls, 1, 64);
        sls += __shfl_xor(sls, 2, 64);
        if (q == 0) sq_s[r] = sls;
    }

    // ---- stage B (per-component) ----
    {
        const int k  = tid >> 2;
        const int q  = tid & 3;
        const int v0 = q * 16;
        const int gb = k * 64 + v0;
        float s = 0.f, g = 0.f;
        unsigned int* pi2 = (unsigned int*)&Bi2[k * LDA + v0];
        unsigned int* pm1 = (unsigned int*)&Bm1[k * LDA + v0];
        #pragma unroll
        for (int i = 0; i < 4; ++i) {
            float4 mu4 = *(const float4*)&pmu_g[gb + 4 * i];
            float4 lg4 = *(const float4*)&plog_g[gb + 4 * i];
            float m0[4] = {mu4.x, mu4.y, mu4.z, mu4.w};
            float l0[4] = {lg4.x, lg4.y, lg4.z, lg4.w};
            float i2v[4], m1v[4];
            #pragma unroll
            for (int j = 0; j < 4; ++j) {
                float i2 = 0.5f * __expf(-2.f * l0[j]);
                i2v[j] = i2;
                m1v[j] = m0[j] * i2;
                g = fmaf(m0[j] * m0[j], i2, g);
                s += l0[j];
            }
            pi2[i * 2 + 0] = pack2(i2v[0], i2v[1]);
            pi2[i * 2 + 1] = pack2(i2v[2], i2v[3]);
            pm1[i * 2 + 0] = pack2(m1v[0], m1v[1]);
            pm1[i * 2 + 1] = pack2(m1v[2], m1v[3]);
        }
        s += __shfl_xor(s, 1, 64);
        s += __shfl_xor(s, 2, 64);
        g += __shfl_xor(g, 1, 64);
        g += __shfl_xor(g, 2, 64);
        if (q == 0) {
            Sk_s[k] = s;
            Gk_s[k] = g;
            Ck_s[k] = -s - 32.0f * LOG2PI_F;
        }
    }
    __syncthreads();

    // ---- MFMA phase ----
    const int lane  = tid & 63;
    const int wid   = tid >> 6;
    const int mm    = lane & 15;
    const int quad  = lane >> 4;
    const int rbase = wid * 16;

    const short8 az2_0 = *(const short8*)&Az2[(rbase + mm) * LDA + quad * 8];
    const short8 az2_1 = *(const short8*)&Az2[(rbase + mm) * LDA + 32 + quad * 8];
    const short8 azm_0 = *(const short8*)&Azm[(rbase + mm) * LDA + quad * 8];
    const short8 azm_1 = *(const short8*)&Azm[(rbase + mm) * LDA + 32 + quad * 8];
    const short8 aq2_0 = *(const short8*)&Aq2[(rbase + mm) * LDA + quad * 8];
    const short8 aq2_1 = *(const short8*)&Aq2[(rbase + mm) * LDA + 32 + quad * 8];
    const short8 aqm_0 = *(const short8*)&Aqm[(rbase + mm) * LDA + quad * 8];
    const short8 aqm_1 = *(const short8*)&Aqm[(rbase + mm) * LDA + 32 + quad * 8];

    floatx4 acc_a[4], acc_c[4];
    #pragma unroll
    for (int t = 0; t < 4; ++t) {
        const int kr = t * 16 + mm;
        const short8 bi0 = *(const short8*)&Bi2[kr * LDA + quad * 8];
        const short8 bi1 = *(const short8*)&Bi2[kr * LDA + 32 + quad * 8];
        const short8 bm0 = *(const short8*)&Bm1[kr * LDA + quad * 8];
        const short8 bm1 = *(const short8*)&Bm1[kr * LDA + 32 + quad * 8];
        floatx4 ca = {0.f, 0.f, 0.f, 0.f};
        ca = __builtin_amdgcn_mfma_f32_16x16x32_bf16(az2_0, bi0, ca, 0, 0, 0);
        ca = __builtin_amdgcn_mfma_f32_16x16x32_bf16(az2_1, bi1, ca, 0, 0, 0);
        ca = __builtin_amdgcn_mfma_f32_16x16x32_bf16(azm_0, bm0, ca, 0, 0, 0);
        ca = __builtin_amdgcn_mfma_f32_16x16x32_bf16(azm_1, bm1, ca, 0, 0, 0);
        acc_a[t] = ca;
        floatx4 cc = {0.f, 0.f, 0.f, 0.f};
        cc = __builtin_amdgcn_mfma_f32_16x16x32_bf16(aq2_0, bi0, cc, 0, 0, 0);
        cc = __builtin_amdgcn_mfma_f32_16x16x32_bf16(aq2_1, bi1, cc, 0, 0, 0);
        cc = __builtin_amdgcn_mfma_f32_16x16x32_bf16(aqm_0, bm0, cc, 0, 0, 0);
        cc = __builtin_amdgcn_mfma_f32_16x16x32_bf16(aqm_1, bm1, cc, 0, 0, 0);
        acc_c[t] = cc;
    }

    // ---- epilogue: softmax over k (in-wave), KL accumulation ----
    float comp[4][4], pz[4][4];
    #pragma unroll
    for (int t = 0; t < 4; ++t) {
        const int k = t * 16 + mm;
        const float ck = Ck_s[k], gk = Gk_s[k];
        #pragma unroll
        for (int r = 0; r < 4; ++r) {
            const int gb = row0 + rbase + quad * 4 + r;
            comp[t][r] = ck - (acc_a[t][r] + gk);
            pz[t][r] = comp[t][r] + __logf(pi[gb * 64 + k]);
        }
    }

    float kly = 0.f, klz = 0.f;
    #pragma unroll
    for (int r = 0; r < 4; ++r) {
        float mx = fmaxf(fmaxf(pz[0][r], pz[1][r]), fmaxf(pz[2][r], pz[3][r]));
        #pragma unroll
        for (int o = 1; o <= 8; o <<= 1) mx = fmaxf(mx, __shfl_xor(mx, o, 64));
        float e[4];
        float s = 0.f;
        #pragma unroll
        for (int t = 0; t < 4; ++t) { e[t] = __expf(pz[t][r] - mx); s += e[t]; }
        #pragma unroll
        for (int o = 1; o <= 8; o <<= 1) s += __shfl_xor(s, o, 64);
        const float lse = mx + __logf(s);
        const float inv = __frcp_rn(s);
        const float sql = sq_s[rbase + quad * 4 + r];
        #pragma unroll
        for (int t = 0; t < 4; ++t) {
            const int k = t * 16 + mm;
            const float p = e[t] * inv;
            kly = fmaf(p, comp[t][r] - lse, kly);
            const float cv = acc_c[t][r] + Gk_s[k];
            klz = fmaf(p, Sk_s[k] - sql + cv - 32.0f, klz);
        }
    }

    kly = wave_sum(kly);
    klz = wave_sum(klz);
    if (lane == 0) { r1[wid] = kly; r2[wid] = klz; }
    __syncthreads();
    if (tid == 0) {
        atomicAdd(&acc[1], (double)(r1[0] + r1[1] + r1[2] + r1[3]));
        atomicAdd(&acc[2], (double)(r2[0] + r2[1] + r2[2] + r2[3]));
    }
}

// MFMA decoder: 16 rows/block, 4 waves split the 49 column tiles.
__global__ __launch_bounds__(256) void decoder_mfma_kernel(
    const float* __restrict__ x, const float* __restrict__ qmu,
    const float* __restrict__ qls, const float* __restrict__ eps,
    const unsigned short* __restrict__ Wt, const float* __restrict__ bd,
    double* __restrict__ acc)
{
    __shared__ unsigned short zt[16 * 64];
    __shared__ float rs[4];
    const int tid  = threadIdx.x;
    const int row0 = blockIdx.x * 16;

    for (int i = tid; i < 16 * 64; i += 256) {
        int g = row0 * 64 + i;
        float z = fmaf(__expf(qls[g]), eps[g], qmu[g]);
        zt[i] = f2bf(z);
    }
    __syncthreads();

    const int lane = tid & 63;
    const int wid  = tid >> 6;
    const int m    = lane & 15;
    const int quad = lane >> 4;

    const short8 af0 = *(const short8*)&zt[m * 64 + quad * 8];
    const short8 af1 = *(const short8*)&zt[m * 64 + 32 + quad * 8];

    float accl = 0.f;
    #pragma unroll 1
    for (int t = wid; t < 49; t += 4) {
        const int col = t * 16 + m;
        float x0 = x[(row0 + quad * 4 + 0) * XD + col];
        float x1 = x[(row0 + quad * 4 + 1) * XD + col];
        float x2 = x[(row0 + quad * 4 + 2) * XD + col];
        float x3 = x[(row0 + quad * 4 + 3) * XD + col];
        float b0 = bd[col];
        const short8 bf0 = *(const short8*)&Wt[col * 64 + quad * 8];
        const short8 bf1 = *(const short8*)&Wt[col * 64 + 32 + quad * 8];
        floatx4 c = {0.f, 0.f, 0.f, 0.f};
        c = __builtin_amdgcn_mfma_f32_16x16x32_bf16(af0, bf0, c, 0, 0, 0);
        c = __builtin_amdgcn_mfma_f32_16x16x32_bf16(af1, bf1, c, 0, 0, 0);
        float d0 = x0 - (c[0] + b0);
        float d1 = x1 - (c[1] + b0);
        float d2 = x2 - (c[2] + b0);
        float d3 = x3 - (c[3] + b0);
        accl = fmaf(d0, d0, accl);
        accl = fmaf(d1, d1, accl);
        accl = fmaf(d2, d2, accl);
        accl = fmaf(d3, d3, accl);
    }

    float s = wave_sum(accl);
    if (lane == 0) rs[wid] = s;
    __syncthreads();
    if (tid == 0)
        atomicAdd(&acc[0], (double)(-0.5f * (rs[0] + rs[1] + rs[2] + rs[3])));
}

__global__ void finalize_kernel(const double* __restrict__ acc, float* __restrict__ out) {
    if (threadIdx.x == 0) {
        double lpx = acc[0] - 0.5 * 1.8378770664093453 * (double)NB * (double)XD;
        double elbo = (lpx - acc[1] - acc[2]) / (double)NB;
        out[0] = (float)elbo;
    }
}

extern "C" void kernel_launch(void* const* d_in, const int* in_sizes, int n_in,
                              void* d_out, int out_size, void* d_ws, size_t ws_size,
                              hipStream_t stream) {
    const float* x    = (const float*)d_in[0];
    const float* pi   = (const float*)d_in[1];
    const float* qmu  = (const float*)d_in[2];
    const float* qls  = (const float*)d_in[3];
    const float* eps  = (const float*)d_in[4];
    const float* pmu  = (const float*)d_in[5];
    const float* plog = (const float*)d_in[6];
    const float* W    = (const float*)d_in[7];
    const float* bd   = (const float*)d_in[8];
    float* out = (float*)d_out;
    double* acc = (double*)d_ws;
    unsigned short* Wt = (unsigned short*)((char*)d_ws + 256);

    prep_kernel<<<(ZD * XD + 255) / 256, 256, 0, stream>>>(W, Wt, acc);
    mixture_mfma_kernel<<<NB / 64, 256, 0, stream>>>(pi, qmu, qls, eps, pmu, plog, acc);
    decoder_mfma_kernel<<<NB / 16, 256, 0, stream>>>(x, qmu, qls, eps, Wt, bd, acc);
    finalize_kernel<<<1, 64, 0, stream>>>(acc, out);
}

// Round 4
// 127.172 us; speedup vs baseline: 1.6166x; 1.0755x over previous
//
#include <hip/hip_runtime.h>

#define NB 16384
#define XD 784
#define ZD 64
#define KK 64
#define LOG2PI_F 1.8378770664093453f
#define LDA 72   // padded row (shorts) for bf16 LDS tiles

typedef __attribute__((ext_vector_type(8))) short short8;
typedef __attribute__((ext_vector_type(4))) float floatx4;

// ws layout:
//   [0 .. 100352)            : Wt[784][64] bf16 (transposed decoder weight)
//   float* fp = ws + 100352  : fp[0..1024)   decoder per-block partials
//                              fp[1024..1280) kl_y per-block partials
//                              fp[1280..1536) kl_z per-block partials
// No atomics anywhere: every slot is written unconditionally each call.

__device__ __forceinline__ float wave_sum(float x) {
    #pragma unroll
    for (int o = 32; o > 0; o >>= 1) x += __shfl_xor(x, o, 64);
    return x;
}

__device__ __forceinline__ unsigned short f2bf(float f) {
    unsigned u = __float_as_uint(f);
    unsigned r = (u + 0x7FFF + ((u >> 16) & 1)) >> 16;  // RNE
    return (unsigned short)r;
}

__device__ __forceinline__ unsigned int pack2(float a, float b) {
    return (unsigned int)f2bf(a) | ((unsigned int)f2bf(b) << 16);
}

__global__ __launch_bounds__(256) void prep_kernel(
    const float* __restrict__ W, unsigned short* __restrict__ Wt)
{
    int idx = blockIdx.x * 256 + threadIdx.x;
    if (idx < ZD * XD) {
        int k = idx / XD;
        int n = idx - k * XD;
        Wt[n * ZD + k] = f2bf(W[idx]);
    }
}

// MFMA mixture: 64 rows/block, 4 waves; wave w owns rows w*16..w*16+15 x all 64 k.
__global__ __launch_bounds__(256) void mixture_mfma_kernel(
    const float* __restrict__ pi, const float* __restrict__ qmu,
    const float* __restrict__ qls, const float* __restrict__ eps,
    const float* __restrict__ pmu_g, const float* __restrict__ plog_g,
    float* __restrict__ kly_p, float* __restrict__ klz_p)
{
    __shared__ unsigned short Az2[64 * LDA];
    __shared__ unsigned short Azm[64 * LDA];
    __shared__ unsigned short Aq2[64 * LDA];
    __shared__ unsigned short Aqm[64 * LDA];
    __shared__ unsigned short Bi2[64 * LDA];
    __shared__ unsigned short Bm1[64 * LDA];
    __shared__ float Ck_s[KK], Sk_s[KK], Gk_s[KK], sq_s[64];
    __shared__ float r1[4], r2[4];

    const int tid  = threadIdx.x;
    const int row0 = blockIdx.x * 64;

    // ---- stage A (per-row) ----
    {
        const int r  = tid >> 2;
        const int q  = tid & 3;
        const int v0 = q * 16;
        const int gb = (row0 + r) * 64 + v0;
        float4 mu4[4], ls4[4], ep4[4];
        #pragma unroll
        for (int i = 0; i < 4; ++i) {
            mu4[i] = *(const float4*)&qmu[gb + 4 * i];
            ls4[i] = *(const float4*)&qls[gb + 4 * i];
            ep4[i] = *(const float4*)&eps[gb + 4 * i];
        }
        float sls = 0.f;
        unsigned int* pz2 = (unsigned int*)&Az2[r * LDA + v0];
        unsigned int* pzm = (unsigned int*)&Azm[r * LDA + v0];
        unsigned int* pq2 = (unsigned int*)&Aq2[r * LDA + v0];
        unsigned int* pqm = (unsigned int*)&Aqm[r * LDA + v0];
        #pragma unroll
        for (int i = 0; i < 4; ++i) {
            float m0[4] = {mu4[i].x, mu4[i].y, mu4[i].z, mu4[i].w};
            float l0[4] = {ls4[i].x, ls4[i].y, ls4[i].z, ls4[i].w};
            float e0[4] = {ep4[i].x, ep4[i].y, ep4[i].z, ep4[i].w};
            float z[4], q2[4];
            #pragma unroll
            for (int j = 0; j < 4; ++j) {
                float qs = __expf(l0[j]);
                z[j]  = fmaf(qs, e0[j], m0[j]);
                q2[j] = fmaf(m0[j], m0[j], qs * qs);
                sls += l0[j];
            }
            pz2[i * 2 + 0] = pack2(z[0] * z[0], z[1] * z[1]);
            pz2[i * 2 + 1] = pack2(z[2] * z[2], z[3] * z[3]);
            pzm[i * 2 + 0] = pack2(-2.f * z[0], -2.f * z[1]);
            pzm[i * 2 + 1] = pack2(-2.f * z[2], -2.f * z[3]);
            pq2[i * 2 + 0] = pack2(q2[0], q2[1]);
            pq2[i * 2 + 1] = pack2(q2[2], q2[3]);
            pqm[i * 2 + 0] = pack2(-2.f * m0[0], -2.f * m0[1]);
            pqm[i * 2 + 1] = pack2(-2.f * m0[2], -2.f * m0[3]);
        }
        sls += __shfl_xor(sls, 1, 64);
        sls += __shfl_xor(sls, 2, 64);
        if (q == 0) sq_s[r] = sls;
    }

    // ---- stage B (per-component) ----
    {
        const int k  = tid >> 2;
        const int q  = tid & 3;
        const int v0 = q * 16;
        const int gb = k * 64 + v0;
        float s = 0.f, g = 0.f;
        unsigned int* pi2 = (unsigned int*)&Bi2[k * LDA + v0];
        unsigned int* pm1 = (unsigned int*)&Bm1[k * LDA + v0];
        #pragma unroll
        for (int i = 0; i < 4; ++i) {
            float4 mu4 = *(const float4*)&pmu_g[gb + 4 * i];
            float4 lg4 = *(const float4*)&plog_g[gb + 4 * i];
            float m0[4] = {mu4.x, mu4.y, mu4.z, mu4.w};
            float l0[4] = {lg4.x, lg4.y, lg4.z, lg4.w};
            float i2v[4], m1v[4];
            #pragma unroll
            for (int j = 0; j < 4; ++j) {
                float i2 = 0.5f * __expf(-2.f * l0[j]);
                i2v[j] = i2;
                m1v[j] = m0[j] * i2;
                g = fmaf(m0[j] * m0[j], i2, g);
                s += l0[j];
            }
            pi2[i * 2 + 0] = pack2(i2v[0], i2v[1]);
            pi2[i * 2 + 1] = pack2(i2v[2], i2v[3]);
            pm1[i * 2 + 0] = pack2(m1v[0], m1v[1]);
            pm1[i * 2 + 1] = pack2(m1v[2], m1v[3]);
        }
        s += __shfl_xor(s, 1, 64);
        s += __shfl_xor(s, 2, 64);
        g += __shfl_xor(g, 1, 64);
        g += __shfl_xor(g, 2, 64);
        if (q == 0) {
            Sk_s[k] = s;
            Gk_s[k] = g;
            Ck_s[k] = -s - 32.0f * LOG2PI_F;
        }
    }
    __syncthreads();

    // ---- MFMA phase ----
    const int lane  = tid & 63;
    const int wid   = tid >> 6;
    const int mm    = lane & 15;
    const int quad  = lane >> 4;
    const int rbase = wid * 16;

    const short8 az2_0 = *(const short8*)&Az2[(rbase + mm) * LDA + quad * 8];
    const short8 az2_1 = *(const short8*)&Az2[(rbase + mm) * LDA + 32 + quad * 8];
    const short8 azm_0 = *(const short8*)&Azm[(rbase + mm) * LDA + quad * 8];
    const short8 azm_1 = *(const short8*)&Azm[(rbase + mm) * LDA + 32 + quad * 8];
    const short8 aq2_0 = *(const short8*)&Aq2[(rbase + mm) * LDA + quad * 8];
    const short8 aq2_1 = *(const short8*)&Aq2[(rbase + mm) * LDA + 32 + quad * 8];
    const short8 aqm_0 = *(const short8*)&Aqm[(rbase + mm) * LDA + quad * 8];
    const short8 aqm_1 = *(const short8*)&Aqm[(rbase + mm) * LDA + 32 + quad * 8];

    floatx4 acc_a[4], acc_c[4];
    #pragma unroll
    for (int t = 0; t < 4; ++t) {
        const int kr = t * 16 + mm;
        const short8 bi0 = *(const short8*)&Bi2[kr * LDA + quad * 8];
        const short8 bi1 = *(const short8*)&Bi2[kr * LDA + 32 + quad * 8];
        const short8 bm0 = *(const short8*)&Bm1[kr * LDA + quad * 8];
        const short8 bm1 = *(const short8*)&Bm1[kr * LDA + 32 + quad * 8];
        floatx4 ca = {0.f, 0.f, 0.f, 0.f};
        ca = __builtin_amdgcn_mfma_f32_16x16x32_bf16(az2_0, bi0, ca, 0, 0, 0);
        ca = __builtin_amdgcn_mfma_f32_16x16x32_bf16(az2_1, bi1, ca, 0, 0, 0);
        ca = __builtin_amdgcn_mfma_f32_16x16x32_bf16(azm_0, bm0, ca, 0, 0, 0);
        ca = __builtin_amdgcn_mfma_f32_16x16x32_bf16(azm_1, bm1, ca, 0, 0, 0);
        acc_a[t] = ca;
        floatx4 cc = {0.f, 0.f, 0.f, 0.f};
        cc = __builtin_amdgcn_mfma_f32_16x16x32_bf16(aq2_0, bi0, cc, 0, 0, 0);
        cc = __builtin_amdgcn_mfma_f32_16x16x32_bf16(aq2_1, bi1, cc, 0, 0, 0);
        cc = __builtin_amdgcn_mfma_f32_16x16x32_bf16(aqm_0, bm0, cc, 0, 0, 0);
        cc = __builtin_amdgcn_mfma_f32_16x16x32_bf16(aqm_1, bm1, cc, 0, 0, 0);
        acc_c[t] = cc;
    }

    // ---- epilogue ----
    float comp[4][4], pz[4][4];
    #pragma unroll
    for (int t = 0; t < 4; ++t) {
        const int k = t * 16 + mm;
        const float ck = Ck_s[k], gk = Gk_s[k];
        #pragma unroll
        for (int r = 0; r < 4; ++r) {
            const int gb = row0 + rbase + quad * 4 + r;
            comp[t][r] = ck - (acc_a[t][r] + gk);
            pz[t][r] = comp[t][r] + __logf(pi[gb * 64 + k]);
        }
    }

    float kly = 0.f, klz = 0.f;
    #pragma unroll
    for (int r = 0; r < 4; ++r) {
        float mx = fmaxf(fmaxf(pz[0][r], pz[1][r]), fmaxf(pz[2][r], pz[3][r]));
        #pragma unroll
        for (int o = 1; o <= 8; o <<= 1) mx = fmaxf(mx, __shfl_xor(mx, o, 64));
        float e[4];
        float s = 0.f;
        #pragma unroll
        for (int t = 0; t < 4; ++t) { e[t] = __expf(pz[t][r] - mx); s += e[t]; }
        #pragma unroll
        for (int o = 1; o <= 8; o <<= 1) s += __shfl_xor(s, o, 64);
        const float lse = mx + __logf(s);
        const float inv = __frcp_rn(s);
        const float sql = sq_s[rbase + quad * 4 + r];
        #pragma unroll
        for (int t = 0; t < 4; ++t) {
            const int k = t * 16 + mm;
            const float p = e[t] * inv;
            kly = fmaf(p, comp[t][r] - lse, kly);
            const float cv = acc_c[t][r] + Gk_s[k];
            klz = fmaf(p, Sk_s[k] - sql + cv - 32.0f, klz);
        }
    }

    kly = wave_sum(kly);
    klz = wave_sum(klz);
    if (lane == 0) { r1[wid] = kly; r2[wid] = klz; }
    __syncthreads();
    if (tid == 0) {
        kly_p[blockIdx.x] = r1[0] + r1[1] + r1[2] + r1[3];
        klz_p[blockIdx.x] = r2[0] + r2[1] + r2[2] + r2[3];
    }
}

// MFMA decoder, software-pipelined tile loop; per-block partial store (no atomics).
__global__ __launch_bounds__(256) void decoder_mfma_kernel(
    const float* __restrict__ x, const float* __restrict__ qmu,
    const float* __restrict__ qls, const float* __restrict__ eps,
    const unsigned short* __restrict__ Wt, const float* __restrict__ bd,
    float* __restrict__ dec_p)
{
    __shared__ unsigned short zt[16 * 64];
    __shared__ float rs[4];
    const int tid  = threadIdx.x;
    const int row0 = blockIdx.x * 16;

    for (int i = tid; i < 16 * 64; i += 256) {
        int g = row0 * 64 + i;
        float z = fmaf(__expf(qls[g]), eps[g], qmu[g]);
        zt[i] = f2bf(z);
    }
    __syncthreads();

    const int lane = tid & 63;
    const int wid  = tid >> 6;
    const int m    = lane & 15;
    const int quad = lane >> 4;

    const short8 af0 = *(const short8*)&zt[m * 64 + quad * 8];
    const short8 af1 = *(const short8*)&zt[m * 64 + 32 + quad * 8];

    const int xrow = (row0 + quad * 4) * XD;

    // prefetch tile wid
    float xa0, xa1, xa2, xa3, bb;
    short8 w0, w1;
    {
        const int col = wid * 16 + m;
        xa0 = x[xrow + 0 * XD + col];
        xa1 = x[xrow + 1 * XD + col];
        xa2 = x[xrow + 2 * XD + col];
        xa3 = x[xrow + 3 * XD + col];
        bb  = bd[col];
        w0  = *(const short8*)&Wt[col * 64 + quad * 8];
        w1  = *(const short8*)&Wt[col * 64 + 32 + quad * 8];
    }

    float accl = 0.f;
    #pragma unroll 1
    for (int t = wid; t < 49; t += 4) {
        const float cx0 = xa0, cx1 = xa1, cx2 = xa2, cx3 = xa3, cb = bb;
        const short8 cw0 = w0, cw1 = w1;
        const int tn = t + 4;
        if (tn < 49) {
            const int col = tn * 16 + m;
            xa0 = x[xrow + 0 * XD + col];
            xa1 = x[xrow + 1 * XD + col];
            xa2 = x[xrow + 2 * XD + col];
            xa3 = x[xrow + 3 * XD + col];
            bb  = bd[col];
            w0  = *(const short8*)&Wt[col * 64 + quad * 8];
            w1  = *(const short8*)&Wt[col * 64 + 32 + quad * 8];
        }
        floatx4 c = {0.f, 0.f, 0.f, 0.f};
        c = __builtin_amdgcn_mfma_f32_16x16x32_bf16(af0, cw0, c, 0, 0, 0);
        c = __builtin_amdgcn_mfma_f32_16x16x32_bf16(af1, cw1, c, 0, 0, 0);
        float d0 = cx0 - (c[0] + cb);
        float d1 = cx1 - (c[1] + cb);
        float d2 = cx2 - (c[2] + cb);
        float d3 = cx3 - (c[3] + cb);
        accl = fmaf(d0, d0, accl);
        accl = fmaf(d1, d1, accl);
        accl = fmaf(d2, d2, accl);
        accl = fmaf(d3, d3, accl);
    }

    float s = wave_sum(accl);
    if (lane == 0) rs[wid] = s;
    __syncthreads();
    if (tid == 0)
        dec_p[blockIdx.x] = -0.5f * (rs[0] + rs[1] + rs[2] + rs[3]);
}

// Single-block reduction of all partials -> elbo.
__global__ __launch_bounds__(256) void finalize_kernel(
    const float* __restrict__ dec_p, const float* __restrict__ kly_p,
    const float* __restrict__ klz_p, float* __restrict__ out)
{
    __shared__ double s0[256], s1[256], s2[256];
    const int tid = threadIdx.x;
    double a0 = 0.0, a1 = 0.0, a2 = 0.0;
    for (int i = tid; i < 1024; i += 256) a0 += (double)dec_p[i];
    a1 = (double)kly_p[tid];
    a2 = (double)klz_p[tid];
    s0[tid] = a0; s1[tid] = a1; s2[tid] = a2;
    __syncthreads();
    #pragma unroll
    for (int off = 128; off > 0; off >>= 1) {
        if (tid < off) {
            s0[tid] += s0[tid + off];
            s1[tid] += s1[tid + off];
            s2[tid] += s2[tid + off];
        }
        __syncthreads();
    }
    if (tid == 0) {
        double lpx = s0[0] - 0.5 * 1.8378770664093453 * (double)NB * (double)XD;
        out[0] = (float)((lpx - s1[0] - s2[0]) / (double)NB);
    }
}

extern "C" void kernel_launch(void* const* d_in, const int* in_sizes, int n_in,
                              void* d_out, int out_size, void* d_ws, size_t ws_size,
                              hipStream_t stream) {
    const float* x    = (const float*)d_in[0];
    const float* pi   = (const float*)d_in[1];
    const float* qmu  = (const float*)d_in[2];
    const float* qls  = (const float*)d_in[3];
    const float* eps  = (const float*)d_in[4];
    const float* pmu  = (const float*)d_in[5];
    const float* plog = (const float*)d_in[6];
    const float* W    = (const float*)d_in[7];
    const float* bd   = (const float*)d_in[8];
    float* out = (float*)d_out;

    unsigned short* Wt = (unsigned short*)d_ws;                 // 100352 B
    float* fp    = (float*)((char*)d_ws + 100352);
    float* dec_p = fp;           // 1024
    float* kly_p = fp + 1024;    // 256
    float* klz_p = fp + 1280;    // 256

    prep_kernel<<<(ZD * XD + 255) / 256, 256, 0, stream>>>(W, Wt);
    mixture_mfma_kernel<<<NB / 64, 256, 0, stream>>>(pi, qmu, qls, eps, pmu, plog, kly_p, klz_p);
    decoder_mfma_kernel<<<NB / 16, 256, 0, stream>>>(x, qmu, qls, eps, Wt, bd, dec_p);
    finalize_kernel<<<1, 256, 0, stream>>>(dec_p, kly_p, klz_p, out);
}